// Round 11
// baseline (654.742 us; speedup 1.0000x reference)
//
#include <hip/hip_runtime.h>

// Problem constants (from reference)
#define N_NODES 50000
#define E_EDGES 1600000
#define HOPS    3
#define KDIM    256      // IN_F
#define NOUT    768      // IN_F * HOP (concatenated hop outputs)
#define MPAD    50048    // 391 * 128  (GEMM M padding)
#define NPS     50176    // 196*256 (coarse bins * fine bins per hop)
#define NCB     196      // coarse bins per hop (src>>8)
#define NCB_ALL (NCB * HOPS)   // 588
#define HSTRIDE ((size_t)MPAD * 256)   // per-hop H plane (hop-major layout)
#define PCAP    10240    // packed-bin placement capacity (mean 8192 + 22 sigma)
#define RCAP    9216     // fine-kernel register stage capacity (mean + 11 sigma)
#define SEB     4096     // split1 edges per block
#define AGG_GRID 2048    // 8 blocks/CU x 256 CU (wave-persistent grid-stride)
#define NGROUPS (N_NODES / 4)   // 12500 node-groups of 4

typedef unsigned short u16;
typedef __bf16 bf16x8 __attribute__((ext_vector_type(8)));
typedef float  f32x4  __attribute__((ext_vector_type(4)));

__device__ __forceinline__ u16 f2bf(float f) {
  unsigned u = __float_as_uint(f);
  u += 0x7fffu + ((u >> 16) & 1u);   // RNE
  return (u16)(u >> 16);
}
__device__ __forceinline__ float bf2f(u16 h) {
  return __uint_as_float(((unsigned)h) << 16);
}

__device__ __forceinline__ void gl2lds16(const void* g, void* l) {
  __builtin_amdgcn_global_load_lds(
      (__attribute__((address_space(1))) void*)(g),
      (__attribute__((address_space(3))) void*)(l), 16, 0, 0);
}

// ---------------- input conversion: f32 -> bf16, pad rows [50000,MPAD) with 0
// Block 0 also seeds the 588 per-bin placement cursors (ccur[b] = b*PCAP).
__global__ __launch_bounds__(256) void conv_a(const float* __restrict__ in,
                                              u16* __restrict__ A,
                                              int* __restrict__ ccur) {
  if (blockIdx.x == 0) {
    for (int i = threadIdx.x; i < NCB_ALL; i += 256) ccur[i] = i * PCAP;
  }
  int idx  = blockIdx.x * 256 + threadIdx.x;   // group of 4 elements
  int base = idx * 4;                          // < MPAD*KDIM
  int row  = base >> 8;
  ushort4 o;
  if (row < N_NODES) {
    float4 v = *(const float4*)(in + base);
    o.x = f2bf(v.x); o.y = f2bf(v.y); o.z = f2bf(v.z); o.w = f2bf(v.w);
  } else {
    o.x = 0; o.y = 0; o.z = 0; o.w = 0;
  }
  *(ushort4*)(A + base) = o;
}

// ---------------- W (768x256 row-major) -> Bt (768x256, K-contig) in bf16
__global__ __launch_bounds__(256) void conv_w(const float* __restrict__ W,
                                              u16* __restrict__ Bt) {
  __shared__ float tile[32][33];
  int h  = blockIdx.z;
  int c0 = blockIdx.x * 32;
  int k0 = blockIdx.y * 32;
  int x  = threadIdx.x & 31;
  int y0 = threadIdx.x >> 5;  // 0..7
#pragma unroll
  for (int i = 0; i < 4; ++i) {
    int k = k0 + y0 + i * 8;
    tile[y0 + i * 8][x] = W[(size_t)(h * 256 + k) * 256 + (c0 + x)];
  }
  __syncthreads();
#pragma unroll
  for (int i = 0; i < 4; ++i) {
    int c = c0 + y0 + i * 8;
    Bt[(size_t)(h * 256 + c) * 256 + (k0 + x)] = f2bf(tile[x][y0 + i * 8]);
  }
}

// ---------------- bf16 MFMA GEMM: H(hop-major) = A[MPAD x 256] * Bt^T
// Double-buffered LDS, ONE barrier per K-step (measured ~-4us vs serial).
// Fused epilogue: per-row attention pre-scores psrc/pdst -> atomicAdd into
// zeroed ssrc/sdst (replaces the old sdot_kernel and its 77MB H re-read).
__global__ __launch_bounds__(256) void gemm_kernel(const u16* __restrict__ A,
                                                   const u16* __restrict__ B,
                                                   u16* __restrict__ H,
                                                   const float* __restrict__ a,
                                                   float* __restrict__ ssrc,
                                                   float* __restrict__ sdst) {
  __shared__ char lds[32768];          // 2 x (As 8K + Bs 8K)
  int tid  = threadIdx.x;
  int lane = tid & 63;
  int w    = tid >> 6;        // wave 0..3
  int wm   = w >> 1, wn = w & 1;
  int r    = lane & 15, q = lane >> 4;
  int bm   = blockIdx.y * 128, bn = blockIdx.x * 128;

  const u16* Ag0 = A + (size_t)(bm + 2 * w * 16 + r) * KDIM + q * 8;
  const u16* Bg0 = B + (size_t)(bn + 2 * w * 16 + r) * KDIM + q * 8;

  f32x4 zero = {0.f, 0.f, 0.f, 0.f};
  f32x4 acc[4][4];
#pragma unroll
  for (int mt = 0; mt < 4; ++mt)
#pragma unroll
    for (int nt = 0; nt < 4; ++nt) acc[mt][nt] = zero;

#define STAGE(b, kt)                                                      \
  do {                                                                    \
    int ko = (kt) * 32;                                                   \
    char* As_ = lds + (b) * 16384;                                        \
    char* Bs_ = As_ + 8192;                                               \
    gl2lds16(Ag0 + ko,             As_ + (2 * w) * 1024);                 \
    gl2lds16(Ag0 + 16 * KDIM + ko, As_ + (2 * w + 1) * 1024);             \
    gl2lds16(Bg0 + ko,             Bs_ + (2 * w) * 1024);                 \
    gl2lds16(Bg0 + 16 * KDIM + ko, Bs_ + (2 * w + 1) * 1024);             \
  } while (0)

  STAGE(0, 0);
  __syncthreads();   // drains vmcnt(0): tile 0 resident

  for (int kt = 0; kt < 8; ++kt) {
    int cur = kt & 1;
    if (kt < 7) STAGE(cur ^ 1, kt + 1);   // prefetch overlaps compute below
    char* As = lds + cur * 16384;
    char* Bs = As + 8192;
    bf16x8 af[4], bfv[4];
#pragma unroll
    for (int mt = 0; mt < 4; ++mt)
      af[mt] = *(const bf16x8*)(As + (wm * 4 + mt) * 1024 + lane * 16);
#pragma unroll
    for (int nt = 0; nt < 4; ++nt)
      bfv[nt] = *(const bf16x8*)(Bs + (wn * 4 + nt) * 1024 + lane * 16);
#pragma unroll
    for (int mt = 0; mt < 4; ++mt)
#pragma unroll
      for (int nt = 0; nt < 4; ++nt)
        acc[mt][nt] = __builtin_amdgcn_mfma_f32_16x16x32_bf16(
            af[mt], bfv[nt], acc[mt][nt], 0, 0, 0);
    if (kt < 7) __syncthreads();  // completes prefetch + protects read buffer
  }
#undef STAGE

  // ---- fused score partials (before H stores) ----
  int hop = bn >> 8;
  int cbase = (bn & 255) + wn * 64 + r;    // col within hop for nt=0
  float asv[4], adv[4];
#pragma unroll
  for (int nt = 0; nt < 4; ++nt) {
    asv[nt] = a[hop * 512 + cbase + nt * 16];
    adv[nt] = a[hop * 512 + 256 + cbase + nt * 16];
  }
#pragma unroll
  for (int mt = 0; mt < 4; ++mt)
#pragma unroll
    for (int rg = 0; rg < 4; ++rg) {
      float ps = 0.f, pd = 0.f;
#pragma unroll
      for (int nt = 0; nt < 4; ++nt) {
        float v = acc[mt][nt][rg];
        ps += v * asv[nt];
        pd += v * adv[nt];
      }
#pragma unroll
      for (int m = 1; m < 16; m <<= 1) {
        ps += __shfl_xor(ps, m);
        pd += __shfl_xor(pd, m);
      }
      if (r == 0) {
        int row = bm + wm * 64 + mt * 16 + q * 4 + rg;
        if (row < N_NODES) {
          atomicAdd(&ssrc[hop * NPS + row], ps);
          atomicAdd(&sdst[hop * NPS + row], pd);
        }
      }
    }

  // C/D: col = lane&15, row = (lane>>4)*4 + reg; store hop-major
#pragma unroll
  for (int mt = 0; mt < 4; ++mt)
#pragma unroll
    for (int nt = 0; nt < 4; ++nt)
#pragma unroll
      for (int rg = 0; rg < 4; ++rg) {
        int row = bm + wm * 64 + mt * 16 + q * 4 + rg;
        int col = bn + wn * 64 + nt * 16 + r;
        int c = col & 255;
        H[hop * HSTRIDE + (size_t)row * 256 + c] = f2bf(acc[mt][nt][rg]);
      }
}

// ---------------- pass 2: PURE kel permutation into padded bins.
// Score gathers + expf live in fine_kernel (R9: they were split1's real
// cost; after fine's sort, ssrc becomes one coalesced 256-float load per
// block). Record is 4 bytes: (srcLow << 16) | dst. 3 phases, 1.6KB LDS.
__global__ __launch_bounds__(256) void split1_kernel(const int* __restrict__ kel,
                                                     int* __restrict__ ccur,
                                                     int* __restrict__ p1) {
  __shared__ int h[NCB];
  __shared__ int lcur[NCB];            // global write cursor per bin
  int t = threadIdx.x, hop = blockIdx.y;
  for (int i = t; i < NCB; i += 256) h[i] = 0;
  __syncthreads();
  const int* srcp = kel + (size_t)hop * 2 * E_EDGES;
  const int* dstp = srcp + E_EDGES;
  int e0 = blockIdx.x * SEB;
  int esrc[16], edst[16];
#pragma unroll
  for (int i = 0; i < 16; ++i) {
    int e = e0 + i * 256 + t;
    if (e < E_EDGES) {
      esrc[i] = srcp[e];
      edst[i] = dstp[e];
      atomicAdd(&h[esrc[i] >> 8], 1);
    } else {
      esrc[i] = -1;
    }
  }
  __syncthreads();
  // reserve global range per touched bin; seed the block cursor with it
  for (int i = t; i < NCB; i += 256)
    if (h[i]) lcur[i] = atomicAdd(&ccur[hop * NCB + i], h[i]);
  __syncthreads();
  // write each record directly to its global slot
#pragma unroll
  for (int i = 0; i < 16; ++i) {
    if (esrc[i] < 0) continue;
    int src = esrc[i];
    int pos = atomicAdd(&lcur[src >> 8], 1);
    p1[pos] = ((src & 255) << 16) | edst[i];
  }
}

// ---------------- pass 3: per coarse bin, sort by src low byte, compute ee
// (score gather fused here: ssrc = coalesced 256-float LDS load; sdst =
// L2-resident random gather overlapped with the hist phase), emit exact
// per-node offs/counts + final (dst, ee) records. REGISTER-staged
// (9 rec/thread x 1024 threads holds the whole bin). LDS ~3.2 KB.
__global__ __launch_bounds__(1024) void fine_kernel(const int* __restrict__ ccur,
                                                    const int* __restrict__ p1,
                                                    const float* __restrict__ ssrc,
                                                    const float* __restrict__ sdst,
                                                    int2* __restrict__ packed,
                                                    int* __restrict__ offs,
                                                    int* __restrict__ counts) {
  __shared__ float ss[256];
  __shared__ int h2[256];
  __shared__ int lc[256];
  __shared__ int wtot[4], wbase[4];
  int t = threadIdx.x;
  int b = blockIdx.x;
  int hop = b / NCB, bl = b % NCB;
  int base = b * PCAP;
  int cnt = ccur[b] - base;     // cursor end - region start = bin count
  if (cnt > RCAP) cnt = RCAP;   // mean+11sigma, never hit; safety only
  if (t < 256) {
    h2[t] = 0;
    ss[t] = ssrc[hop * NPS + bl * 256 + t];   // coalesced per-node s_src
  }
  __syncthreads();
  const float* sd = sdst + hop * NPS;
  int   r0, r1, r2, r3, r4, r5, r6, r7, r8;   // named: static reg indexing
  float e0, e1, e2, e3, e4, e5, e6, e7, e8;
#define FLOAD(k, rv, ev)                                                 \
  do {                                                                   \
    int idx = (k) * 1024 + t;                                            \
    if (idx < cnt) {                                                     \
      rv = p1[base + idx];                                               \
      int low = (rv >> 16) & 255;                                        \
      atomicAdd(&h2[low], 1);                                            \
      float s = ss[low] + sd[rv & 0xFFFF];                               \
      float lr = s > 0.0f ? s : 0.2f * s;  /* leaky_relu alpha=0.2 */    \
      ev = __expf(-lr);                                                  \
    }                                                                    \
  } while (0)
  FLOAD(0, r0, e0); FLOAD(1, r1, e1); FLOAD(2, r2, e2); FLOAD(3, r3, e3);
  FLOAD(4, r4, e4); FLOAD(5, r5, e5); FLOAD(6, r6, e6); FLOAD(7, r7, e7);
  FLOAD(8, r8, e8);
#undef FLOAD
  __syncthreads();                 // all reads done (hist consumed them)
  int v = 0, s = 0;
  if (t < 256) {
    int lane = t & 63;
    v = h2[t];
    s = v;
#pragma unroll
    for (int d = 1; d < 64; d <<= 1) {
      int x = __shfl_up(s, d);
      if (lane >= d) s += x;
    }
    if (lane == 63) wtot[t >> 6] = s;
  }
  __syncthreads();
  if (t == 0) {
    int r = 0;
#pragma unroll
    for (int i = 0; i < 4; ++i) { wbase[i] = r; r += wtot[i]; }
  }
  __syncthreads();
  if (t < 256) {
    int ex = wbase[t >> 6] + s - v;  // exclusive prefix within bin
    int node = hop * NPS + bl * 256 + t;
    offs[node] = base + ex;
    counts[node] = v;
    lc[t] = ex;
  }
  __syncthreads();
#define FSCAT(k, rv, ev)                                                 \
  do {                                                                   \
    int idx = (k) * 1024 + t;                                            \
    if (idx < cnt) {                                                     \
      int low = (rv >> 16) & 255;                                        \
      int rank = atomicAdd(&lc[low], 1);                                 \
      packed[base + rank] = make_int2(rv & 0xFFFF, __float_as_int(ev));  \
    }                                                                    \
  } while (0)
  FSCAT(0, r0, e0); FSCAT(1, r1, e1); FSCAT(2, r2, e2); FSCAT(3, r3, e3);
  FSCAT(4, r4, e4); FSCAT(5, r5, e5); FSCAT(6, r6, e6); FSCAT(7, r7, e7);
  FSCAT(8, r8, e8);
#undef FSCAT
}

// ---------------- aggregation: wave-persistent grid-stride over node
// groups. 2048 blocks = 8 blocks/CU slot fill; each wave processes ~6
// node-groups sequentially, averaging per-node edge-count variance INSIDE
// the wave instead of across block slot-holding (R10 profile: 12500 small
// blocks left occupancy at 39.6% with VGPR=64 allowing 100%; R6 proved
// grid-stride lifts true occupancy to 76%). PLAIN __launch_bounds__(256):
// NO min-waves pin (R6: (256,8) pinned VGPR=32 -> 2.2GB scratch spills);
// inner loop = exact round-3 form (VGPR 64; 64->65 cliff halves occ, R5).
__device__ __forceinline__ void accum8(float* a, float& rs, float ee, uint4 h) {
  rs += ee;
  a[0] += ee * __uint_as_float(h.x << 16);
  a[1] += ee * __uint_as_float(h.x & 0xffff0000u);
  a[2] += ee * __uint_as_float(h.y << 16);
  a[3] += ee * __uint_as_float(h.y & 0xffff0000u);
  a[4] += ee * __uint_as_float(h.z << 16);
  a[5] += ee * __uint_as_float(h.z & 0xffff0000u);
  a[6] += ee * __uint_as_float(h.w << 16);
  a[7] += ee * __uint_as_float(h.w & 0xffff0000u);
}

__global__ __launch_bounds__(256) void agg_all(const int* __restrict__ offs,
                                               const int* __restrict__ counts,
                                               const int2* __restrict__ packed,
                                               const u16* __restrict__ Hbf,
                                               float* __restrict__ out) {
  int lane = threadIdx.x & 63, wid = threadIdx.x >> 6;
  int half = lane >> 5, sub = lane & 31;

  for (int nb = blockIdx.x; nb < NGROUPS; nb += AGG_GRID) {
    int n = nb * 4 + wid;   // < N_NODES since N_NODES = NGROUPS*4

    float r[8];
#pragma unroll
    for (int c = 0; c < 8; ++c) r[c] = 0.f;

#pragma unroll
    for (int hop = 0; hop < HOPS; ++hop) {
      const float wgt = hop == 0 ? 0.5f : (hop == 1 ? 0.25f : 0.125f);
      int start = offs[hop * NPS + n];
      int cnt = counts[hop * NPS + n];
      const int2* pk = packed + start;
      const u16* Hh = Hbf + hop * HSTRIDE + sub * 8;  // 16B per-lane slice
      float a0[8], a1[8];
      float rs0 = 0.f, rs1 = 0.f;
#pragma unroll
      for (int c = 0; c < 8; ++c) { a0[c] = 0.f; a1[c] = 0.f; }

      int np = cnt >> 1;  // pairs; half-wave h handles edge 2j+h of pair j
      int j = 0;
      for (; j + 8 <= np; j += 8) {
        int2 p[8];
#pragma unroll
        for (int i = 0; i < 8; ++i) p[i] = pk[2 * (j + i) + half];
        uint4 h[8];
#pragma unroll
        for (int i = 0; i < 8; ++i)
          h[i] = *(const uint4*)(Hh + (size_t)p[i].x * 256);
#pragma unroll
        for (int i = 0; i < 8; ++i)
          accum8((i & 1) ? a1 : a0, (i & 1) ? rs1 : rs0,
                 __int_as_float(p[i].y), h[i]);
      }
      for (; j < np; ++j) {
        int2 p = pk[2 * j + half];
        uint4 hv = *(const uint4*)(Hh + (size_t)p.x * 256);
        accum8(a0, rs0, __int_as_float(p.y), hv);
      }
      if (cnt & 1) {
        int2 p = pk[cnt - 1];                       // same addr both halves
        float ee = half ? 0.f : __int_as_float(p.y);
        uint4 hv = *(const uint4*)(Hh + (size_t)p.x * 256);
        accum8(a1, rs1, ee, hv);
      }

      float rs = rs0 + rs1;
      rs += __shfl_xor(rs, 32);
      float inv = wgt / rs;  // cnt==0 -> inf, 0*inf = NaN matches ref 0/0
#pragma unroll
      for (int c = 0; c < 8; ++c) {
        float t = a0[c] + a1[c];
        t += __shfl_xor(t, 32);
        r[c] += t * inv;     // NaN propagates through the blend like RMW did
      }
    }

    // epilogue: elu + single write
    float* op = out + (size_t)n * 256 + sub * 8 + half * 4;
    float4 o;
    float v0 = r[half * 4 + 0], v1 = r[half * 4 + 1];
    float v2 = r[half * 4 + 2], v3 = r[half * 4 + 3];
    o.x = v0 > 0.f ? v0 : expm1f(v0);
    o.y = v1 > 0.f ? v1 : expm1f(v1);
    o.z = v2 > 0.f ? v2 : expm1f(v2);
    o.w = v3 > 0.f ? v3 : expm1f(v3);
    *(float4*)op = o;
  }
}

extern "C" void kernel_launch(void* const* d_in, const int* in_sizes, int n_in,
                              void* d_out, int out_size, void* d_ws, size_t ws_size,
                              hipStream_t stream) {
  const float* input = (const float*)d_in[0];
  const int*   kel   = (const int*)d_in[1];
  const float* W     = (const float*)d_in[2];
  const float* a     = (const float*)d_in[3];
  float* out = (float*)d_out;

  char* ws = (char*)d_ws;
  size_t o = 0;
  u16* Abf = (u16*)(ws + o);   o += (size_t)MPAD * KDIM * 2;   // 25.6 MB
  u16* Bt  = (u16*)(ws + o);   o += (size_t)NOUT * KDIM * 2;   // 0.4 MB
  u16* Hbf = (u16*)(ws + o);   o += (size_t)MPAD * NOUT * 2;   // 76.9 MB (3 hop planes)
  float* ssrc = (float*)(ws + o); o += (size_t)3 * NPS * 4;
  float* sdst = (float*)(ws + o); o += (size_t)3 * NPS * 4;
  int* counts = (int*)(ws + o);   o += (size_t)3 * NPS * 4;
  int* offs   = (int*)(ws + o);   o += (size_t)3 * NPS * 4;
  int* ccur   = (int*)(ws + o);   o += 4096;  // 588 placement cursors
  int2* packed = (int2*)(ws + o); o += (size_t)NCB_ALL * PCAP * 8 + 65536; // 48.2 MB padded bins
  // P1 (24.1 MB, 4B records) overlays Abf: Abf is dead after gemm, and
  // split1 launches after gemm in the serial stream.
  int* p1 = (int*)Abf;

  // ssrc and sdst are adjacent: zero both for the gemm-epilogue atomics
  hipMemsetAsync(ssrc, 0, (size_t)2 * 3 * NPS * 4, stream);

  conv_a<<<MPAD * KDIM / 1024, 256, 0, stream>>>(input, Abf, ccur);
  conv_w<<<dim3(8, 8, 3), 256, 0, stream>>>(W, Bt);
  gemm_kernel<<<dim3(NOUT / 128, MPAD / 128), 256, 0, stream>>>(Abf, Bt, Hbf,
                                                                a, ssrc, sdst);

  int nsplit = (E_EDGES + SEB - 1) / SEB;  // 391
  split1_kernel<<<dim3(nsplit, 3), 256, 0, stream>>>(kel, ccur, p1);
  fine_kernel<<<NCB_ALL, 1024, 0, stream>>>(ccur, p1, ssrc, sdst,
                                            packed, offs, counts);

  agg_all<<<AGG_GRID, 256, 0, stream>>>(offs, counts, packed, Hbf, out);
}

// Round 12
// 619.438 us; speedup vs baseline: 1.0570x; 1.0570x over previous
//
#include <hip/hip_runtime.h>

// Problem constants (from reference)
#define N_NODES 50000
#define E_EDGES 1600000
#define HOPS    3
#define KDIM    256      // IN_F
#define NOUT    768      // IN_F * HOP (concatenated hop outputs)
#define MPAD    50048    // 391 * 128  (GEMM M padding)
#define NPS     50176    // 196*256 (coarse bins * fine bins per hop)
#define NCB     196      // coarse bins per hop (src>>8)
#define NCB_ALL (NCB * HOPS)   // 588
#define HSTRIDE ((size_t)MPAD * 256)   // per-hop H plane (hop-major layout)
#define PCAP    10240    // packed-bin placement capacity (mean 8192 + 22 sigma)
#define RCAP    9216     // fine-kernel register stage capacity (mean + 11 sigma)
#define SEB     4096     // split1 edges per block

typedef unsigned short u16;
typedef __bf16 bf16x8 __attribute__((ext_vector_type(8)));
typedef float  f32x4  __attribute__((ext_vector_type(4)));

__device__ __forceinline__ u16 f2bf(float f) {
  unsigned u = __float_as_uint(f);
  u += 0x7fffu + ((u >> 16) & 1u);   // RNE
  return (u16)(u >> 16);
}
__device__ __forceinline__ float bf2f(u16 h) {
  return __uint_as_float(((unsigned)h) << 16);
}

__device__ __forceinline__ void gl2lds16(const void* g, void* l) {
  __builtin_amdgcn_global_load_lds(
      (__attribute__((address_space(1))) void*)(g),
      (__attribute__((address_space(3))) void*)(l), 16, 0, 0);
}

// ---------------- input conversion: f32 -> bf16, pad rows [50000,MPAD) with 0
// Block 0 also seeds the 588 per-bin placement cursors (ccur[b] = b*PCAP).
__global__ __launch_bounds__(256) void conv_a(const float* __restrict__ in,
                                              u16* __restrict__ A,
                                              int* __restrict__ ccur) {
  if (blockIdx.x == 0) {
    for (int i = threadIdx.x; i < NCB_ALL; i += 256) ccur[i] = i * PCAP;
  }
  int idx  = blockIdx.x * 256 + threadIdx.x;   // group of 4 elements
  int base = idx * 4;                          // < MPAD*KDIM
  int row  = base >> 8;
  ushort4 o;
  if (row < N_NODES) {
    float4 v = *(const float4*)(in + base);
    o.x = f2bf(v.x); o.y = f2bf(v.y); o.z = f2bf(v.z); o.w = f2bf(v.w);
  } else {
    o.x = 0; o.y = 0; o.z = 0; o.w = 0;
  }
  *(ushort4*)(A + base) = o;
}

// ---------------- W (768x256 row-major) -> Bt (768x256, K-contig) in bf16
__global__ __launch_bounds__(256) void conv_w(const float* __restrict__ W,
                                              u16* __restrict__ Bt) {
  __shared__ float tile[32][33];
  int h  = blockIdx.z;
  int c0 = blockIdx.x * 32;
  int k0 = blockIdx.y * 32;
  int x  = threadIdx.x & 31;
  int y0 = threadIdx.x >> 5;  // 0..7
#pragma unroll
  for (int i = 0; i < 4; ++i) {
    int k = k0 + y0 + i * 8;
    tile[y0 + i * 8][x] = W[(size_t)(h * 256 + k) * 256 + (c0 + x)];
  }
  __syncthreads();
#pragma unroll
  for (int i = 0; i < 4; ++i) {
    int c = c0 + y0 + i * 8;
    Bt[(size_t)(h * 256 + c) * 256 + (k0 + x)] = f2bf(tile[x][y0 + i * 8]);
  }
}

// ---------------- bf16 MFMA GEMM: H(hop-major) = A[MPAD x 256] * Bt^T
// Double-buffered LDS, ONE barrier per K-step (measured ~-4us vs serial).
// Fused epilogue: per-row attention pre-scores psrc/pdst -> atomicAdd into
// zeroed ssrc/sdst (replaces the old sdot_kernel and its 77MB H re-read).
__global__ __launch_bounds__(256) void gemm_kernel(const u16* __restrict__ A,
                                                   const u16* __restrict__ B,
                                                   u16* __restrict__ H,
                                                   const float* __restrict__ a,
                                                   float* __restrict__ ssrc,
                                                   float* __restrict__ sdst) {
  __shared__ char lds[32768];          // 2 x (As 8K + Bs 8K)
  int tid  = threadIdx.x;
  int lane = tid & 63;
  int w    = tid >> 6;        // wave 0..3
  int wm   = w >> 1, wn = w & 1;
  int r    = lane & 15, q = lane >> 4;
  int bm   = blockIdx.y * 128, bn = blockIdx.x * 128;

  const u16* Ag0 = A + (size_t)(bm + 2 * w * 16 + r) * KDIM + q * 8;
  const u16* Bg0 = B + (size_t)(bn + 2 * w * 16 + r) * KDIM + q * 8;

  f32x4 zero = {0.f, 0.f, 0.f, 0.f};
  f32x4 acc[4][4];
#pragma unroll
  for (int mt = 0; mt < 4; ++mt)
#pragma unroll
    for (int nt = 0; nt < 4; ++nt) acc[mt][nt] = zero;

#define STAGE(b, kt)                                                      \
  do {                                                                    \
    int ko = (kt) * 32;                                                   \
    char* As_ = lds + (b) * 16384;                                        \
    char* Bs_ = As_ + 8192;                                               \
    gl2lds16(Ag0 + ko,             As_ + (2 * w) * 1024);                 \
    gl2lds16(Ag0 + 16 * KDIM + ko, As_ + (2 * w + 1) * 1024);             \
    gl2lds16(Bg0 + ko,             Bs_ + (2 * w) * 1024);                 \
    gl2lds16(Bg0 + 16 * KDIM + ko, Bs_ + (2 * w + 1) * 1024);             \
  } while (0)

  STAGE(0, 0);
  __syncthreads();   // drains vmcnt(0): tile 0 resident

  for (int kt = 0; kt < 8; ++kt) {
    int cur = kt & 1;
    if (kt < 7) STAGE(cur ^ 1, kt + 1);   // prefetch overlaps compute below
    char* As = lds + cur * 16384;
    char* Bs = As + 8192;
    bf16x8 af[4], bfv[4];
#pragma unroll
    for (int mt = 0; mt < 4; ++mt)
      af[mt] = *(const bf16x8*)(As + (wm * 4 + mt) * 1024 + lane * 16);
#pragma unroll
    for (int nt = 0; nt < 4; ++nt)
      bfv[nt] = *(const bf16x8*)(Bs + (wn * 4 + nt) * 1024 + lane * 16);
#pragma unroll
    for (int mt = 0; mt < 4; ++mt)
#pragma unroll
      for (int nt = 0; nt < 4; ++nt)
        acc[mt][nt] = __builtin_amdgcn_mfma_f32_16x16x32_bf16(
            af[mt], bfv[nt], acc[mt][nt], 0, 0, 0);
    if (kt < 7) __syncthreads();  // completes prefetch + protects read buffer
  }
#undef STAGE

  // ---- fused score partials (before H stores) ----
  int hop = bn >> 8;
  int cbase = (bn & 255) + wn * 64 + r;    // col within hop for nt=0
  float asv[4], adv[4];
#pragma unroll
  for (int nt = 0; nt < 4; ++nt) {
    asv[nt] = a[hop * 512 + cbase + nt * 16];
    adv[nt] = a[hop * 512 + 256 + cbase + nt * 16];
  }
#pragma unroll
  for (int mt = 0; mt < 4; ++mt)
#pragma unroll
    for (int rg = 0; rg < 4; ++rg) {
      float ps = 0.f, pd = 0.f;
#pragma unroll
      for (int nt = 0; nt < 4; ++nt) {
        float v = acc[mt][nt][rg];
        ps += v * asv[nt];
        pd += v * adv[nt];
      }
#pragma unroll
      for (int m = 1; m < 16; m <<= 1) {
        ps += __shfl_xor(ps, m);
        pd += __shfl_xor(pd, m);
      }
      if (r == 0) {
        int row = bm + wm * 64 + mt * 16 + q * 4 + rg;
        if (row < N_NODES) {
          atomicAdd(&ssrc[hop * NPS + row], ps);
          atomicAdd(&sdst[hop * NPS + row], pd);
        }
      }
    }

  // C/D: col = lane&15, row = (lane>>4)*4 + reg; store hop-major
#pragma unroll
  for (int mt = 0; mt < 4; ++mt)
#pragma unroll
    for (int nt = 0; nt < 4; ++nt)
#pragma unroll
      for (int rg = 0; rg < 4; ++rg) {
        int row = bm + wm * 64 + mt * 16 + q * 4 + rg;
        int col = bn + wn * 64 + nt * 16 + r;
        int c = col & 255;
        H[hop * HSTRIDE + (size_t)row * 256 + c] = f2bf(acc[mt][nt][rg]);
      }
}

// ---------------- pass 2: PURE kel permutation into padded bins.
// Score gathers + expf live in fine_kernel (R9: they were split1's real
// cost; after fine's sort, ssrc becomes one coalesced 256-float load per
// block). Record is 4 bytes: (srcLow << 16) | dst. 3 phases, 1.6KB LDS.
__global__ __launch_bounds__(256) void split1_kernel(const int* __restrict__ kel,
                                                     int* __restrict__ ccur,
                                                     int* __restrict__ p1) {
  __shared__ int h[NCB];
  __shared__ int lcur[NCB];            // global write cursor per bin
  int t = threadIdx.x, hop = blockIdx.y;
  for (int i = t; i < NCB; i += 256) h[i] = 0;
  __syncthreads();
  const int* srcp = kel + (size_t)hop * 2 * E_EDGES;
  const int* dstp = srcp + E_EDGES;
  int e0 = blockIdx.x * SEB;
  int esrc[16], edst[16];
#pragma unroll
  for (int i = 0; i < 16; ++i) {
    int e = e0 + i * 256 + t;
    if (e < E_EDGES) {
      esrc[i] = srcp[e];
      edst[i] = dstp[e];
      atomicAdd(&h[esrc[i] >> 8], 1);
    } else {
      esrc[i] = -1;
    }
  }
  __syncthreads();
  // reserve global range per touched bin; seed the block cursor with it
  for (int i = t; i < NCB; i += 256)
    if (h[i]) lcur[i] = atomicAdd(&ccur[hop * NCB + i], h[i]);
  __syncthreads();
  // write each record directly to its global slot
#pragma unroll
  for (int i = 0; i < 16; ++i) {
    if (esrc[i] < 0) continue;
    int src = esrc[i];
    int pos = atomicAdd(&lcur[src >> 8], 1);
    p1[pos] = ((src & 255) << 16) | edst[i];
  }
}

// ---------------- pass 3: per coarse bin, sort by src low byte, compute ee
// (score gather fused here: ssrc = coalesced 256-float LDS load; sdst =
// L2-resident random gather overlapped with the hist phase), emit exact
// per-node offs/counts + final (dst, ee) records. REGISTER-staged
// (9 rec/thread x 1024 threads holds the whole bin). LDS ~3.2 KB.
__global__ __launch_bounds__(1024) void fine_kernel(const int* __restrict__ ccur,
                                                    const int* __restrict__ p1,
                                                    const float* __restrict__ ssrc,
                                                    const float* __restrict__ sdst,
                                                    int2* __restrict__ packed,
                                                    int* __restrict__ offs,
                                                    int* __restrict__ counts) {
  __shared__ float ss[256];
  __shared__ int h2[256];
  __shared__ int lc[256];
  __shared__ int wtot[4], wbase[4];
  int t = threadIdx.x;
  int b = blockIdx.x;
  int hop = b / NCB, bl = b % NCB;
  int base = b * PCAP;
  int cnt = ccur[b] - base;     // cursor end - region start = bin count
  if (cnt > RCAP) cnt = RCAP;   // mean+11sigma, never hit; safety only
  if (t < 256) {
    h2[t] = 0;
    ss[t] = ssrc[hop * NPS + bl * 256 + t];   // coalesced per-node s_src
  }
  __syncthreads();
  const float* sd = sdst + hop * NPS;
  int   r0, r1, r2, r3, r4, r5, r6, r7, r8;   // named: static reg indexing
  float e0, e1, e2, e3, e4, e5, e6, e7, e8;
#define FLOAD(k, rv, ev)                                                 \
  do {                                                                   \
    int idx = (k) * 1024 + t;                                            \
    if (idx < cnt) {                                                     \
      rv = p1[base + idx];                                               \
      int low = (rv >> 16) & 255;                                        \
      atomicAdd(&h2[low], 1);                                            \
      float s = ss[low] + sd[rv & 0xFFFF];                               \
      float lr = s > 0.0f ? s : 0.2f * s;  /* leaky_relu alpha=0.2 */    \
      ev = __expf(-lr);                                                  \
    }                                                                    \
  } while (0)
  FLOAD(0, r0, e0); FLOAD(1, r1, e1); FLOAD(2, r2, e2); FLOAD(3, r3, e3);
  FLOAD(4, r4, e4); FLOAD(5, r5, e5); FLOAD(6, r6, e6); FLOAD(7, r7, e7);
  FLOAD(8, r8, e8);
#undef FLOAD
  __syncthreads();                 // all reads done (hist consumed them)
  int v = 0, s = 0;
  if (t < 256) {
    int lane = t & 63;
    v = h2[t];
    s = v;
#pragma unroll
    for (int d = 1; d < 64; d <<= 1) {
      int x = __shfl_up(s, d);
      if (lane >= d) s += x;
    }
    if (lane == 63) wtot[t >> 6] = s;
  }
  __syncthreads();
  if (t == 0) {
    int r = 0;
#pragma unroll
    for (int i = 0; i < 4; ++i) { wbase[i] = r; r += wtot[i]; }
  }
  __syncthreads();
  if (t < 256) {
    int ex = wbase[t >> 6] + s - v;  // exclusive prefix within bin
    int node = hop * NPS + bl * 256 + t;
    offs[node] = base + ex;
    counts[node] = v;
    lc[t] = ex;
  }
  __syncthreads();
#define FSCAT(k, rv, ev)                                                 \
  do {                                                                   \
    int idx = (k) * 1024 + t;                                            \
    if (idx < cnt) {                                                     \
      int low = (rv >> 16) & 255;                                        \
      int rank = atomicAdd(&lc[low], 1);                                 \
      packed[base + rank] = make_int2(rv & 0xFFFF, __float_as_int(ev));  \
    }                                                                    \
  } while (0)
  FSCAT(0, r0, e0); FSCAT(1, r1, e1); FSCAT(2, r2, e2); FSCAT(3, r3, e3);
  FSCAT(4, r4, e4); FSCAT(5, r5, e5); FSCAT(6, r6, e6); FSCAT(7, r7, e7);
  FSCAT(8, r8, e8);
#undef FSCAT
}

// ---------------- aggregation: 2-wave blocks (128 threads, 2 nodes).
// R10 profile: 4-wave blocks reach only 39.6% occupancy with VGPR=64
// allowing 100% — each block retains 4 wave slots until its SLOWEST wave
// (Poisson edge counts) retires. 2-wave blocks halve that retention with
// the IDENTICAL per-wave body: no loop, no pin, no added registers.
// (R5 +ILP, R6 min-waves pin, R11 grid-stride all broke the 64-VGPR
// budget; this changes geometry only.)
__device__ __forceinline__ void accum8(float* a, float& rs, float ee, uint4 h) {
  rs += ee;
  a[0] += ee * __uint_as_float(h.x << 16);
  a[1] += ee * __uint_as_float(h.x & 0xffff0000u);
  a[2] += ee * __uint_as_float(h.y << 16);
  a[3] += ee * __uint_as_float(h.y & 0xffff0000u);
  a[4] += ee * __uint_as_float(h.z << 16);
  a[5] += ee * __uint_as_float(h.z & 0xffff0000u);
  a[6] += ee * __uint_as_float(h.w << 16);
  a[7] += ee * __uint_as_float(h.w & 0xffff0000u);
}

__global__ __launch_bounds__(128) void agg_all(const int* __restrict__ offs,
                                               const int* __restrict__ counts,
                                               const int2* __restrict__ packed,
                                               const u16* __restrict__ Hbf,
                                               float* __restrict__ out) {
  int lane = threadIdx.x & 63, wid = threadIdx.x >> 6;  // wid 0..1
  int half = lane >> 5, sub = lane & 31;
  int n = blockIdx.x * 2 + wid;   // grid 25000 -> n < 50000 always

  float r[8];
#pragma unroll
  for (int c = 0; c < 8; ++c) r[c] = 0.f;

#pragma unroll
  for (int hop = 0; hop < HOPS; ++hop) {
    const float wgt = hop == 0 ? 0.5f : (hop == 1 ? 0.25f : 0.125f);
    int start = offs[hop * NPS + n];
    int cnt = counts[hop * NPS + n];
    const int2* pk = packed + start;
    const u16* Hh = Hbf + hop * HSTRIDE + sub * 8;  // 16B per-lane column slice
    float a0[8], a1[8];
    float rs0 = 0.f, rs1 = 0.f;
#pragma unroll
    for (int c = 0; c < 8; ++c) { a0[c] = 0.f; a1[c] = 0.f; }

    int np = cnt >> 1;  // pairs; half-wave h handles edge 2j+h of pair j
    int j = 0;
    for (; j + 8 <= np; j += 8) {
      int2 p[8];
#pragma unroll
      for (int i = 0; i < 8; ++i) p[i] = pk[2 * (j + i) + half];
      uint4 h[8];
#pragma unroll
      for (int i = 0; i < 8; ++i) h[i] = *(const uint4*)(Hh + (size_t)p[i].x * 256);
#pragma unroll
      for (int i = 0; i < 8; ++i)
        accum8((i & 1) ? a1 : a0, (i & 1) ? rs1 : rs0, __int_as_float(p[i].y), h[i]);
    }
    for (; j < np; ++j) {
      int2 p = pk[2 * j + half];
      uint4 hv = *(const uint4*)(Hh + (size_t)p.x * 256);
      accum8(a0, rs0, __int_as_float(p.y), hv);
    }
    if (cnt & 1) {
      int2 p = pk[cnt - 1];                       // same addr both halves
      float ee = half ? 0.f : __int_as_float(p.y);
      uint4 hv = *(const uint4*)(Hh + (size_t)p.x * 256);
      accum8(a1, rs1, ee, hv);
    }

    float rs = rs0 + rs1;
    rs += __shfl_xor(rs, 32);
    float inv = wgt / rs;  // cnt==0 -> inf, 0*inf = NaN matches reference 0/0
#pragma unroll
    for (int c = 0; c < 8; ++c) {
      float t = a0[c] + a1[c];
      t += __shfl_xor(t, 32);
      r[c] += t * inv;     // NaN propagates through the blend like the RMW did
    }
  }

  // epilogue: elu + single write
  float* op = out + (size_t)n * 256 + sub * 8 + half * 4;
  float4 o;
  float v0 = r[half * 4 + 0], v1 = r[half * 4 + 1];
  float v2 = r[half * 4 + 2], v3 = r[half * 4 + 3];
  o.x = v0 > 0.f ? v0 : expm1f(v0);
  o.y = v1 > 0.f ? v1 : expm1f(v1);
  o.z = v2 > 0.f ? v2 : expm1f(v2);
  o.w = v3 > 0.f ? v3 : expm1f(v3);
  *(float4*)op = o;
}

extern "C" void kernel_launch(void* const* d_in, const int* in_sizes, int n_in,
                              void* d_out, int out_size, void* d_ws, size_t ws_size,
                              hipStream_t stream) {
  const float* input = (const float*)d_in[0];
  const int*   kel   = (const int*)d_in[1];
  const float* W     = (const float*)d_in[2];
  const float* a     = (const float*)d_in[3];
  float* out = (float*)d_out;

  char* ws = (char*)d_ws;
  size_t o = 0;
  u16* Abf = (u16*)(ws + o);   o += (size_t)MPAD * KDIM * 2;   // 25.6 MB
  u16* Bt  = (u16*)(ws + o);   o += (size_t)NOUT * KDIM * 2;   // 0.4 MB
  u16* Hbf = (u16*)(ws + o);   o += (size_t)MPAD * NOUT * 2;   // 76.9 MB (3 hop planes)
  float* ssrc = (float*)(ws + o); o += (size_t)3 * NPS * 4;
  float* sdst = (float*)(ws + o); o += (size_t)3 * NPS * 4;
  int* counts = (int*)(ws + o);   o += (size_t)3 * NPS * 4;
  int* offs   = (int*)(ws + o);   o += (size_t)3 * NPS * 4;
  int* ccur   = (int*)(ws + o);   o += 4096;  // 588 placement cursors
  int2* packed = (int2*)(ws + o); o += (size_t)NCB_ALL * PCAP * 8 + 65536; // 48.2 MB padded bins
  // P1 (24.1 MB, 4B records) overlays Abf: Abf is dead after gemm, and
  // split1 launches after gemm in the serial stream.
  int* p1 = (int*)Abf;

  // ssrc and sdst are adjacent: zero both for the gemm-epilogue atomics
  hipMemsetAsync(ssrc, 0, (size_t)2 * 3 * NPS * 4, stream);

  conv_a<<<MPAD * KDIM / 1024, 256, 0, stream>>>(input, Abf, ccur);
  conv_w<<<dim3(8, 8, 3), 256, 0, stream>>>(W, Bt);
  gemm_kernel<<<dim3(NOUT / 128, MPAD / 128), 256, 0, stream>>>(Abf, Bt, Hbf,
                                                                a, ssrc, sdst);

  int nsplit = (E_EDGES + SEB - 1) / SEB;  // 391
  split1_kernel<<<dim3(nsplit, 3), 256, 0, stream>>>(kel, ccur, p1);
  fine_kernel<<<NCB_ALL, 1024, 0, stream>>>(ccur, p1, ssrc, sdst,
                                            packed, offs, counts);

  agg_all<<<N_NODES / 2, 128, 0, stream>>>(offs, counts, packed, Hbf, out);
}